// Round 5
// baseline (310.383 us; speedup 1.0000x reference)
//
#include <hip/hip_runtime.h>
#include <math.h>

// ---------------------------------------------------------------------------
// Workspace layout (4B words), total = 128 + N + 12E + E + 192N + 256
//   = 20,050,384 words = 80.2 MB for N=50k, E=800k (size proven in Round 2).
//   cg       [0..128)            CG tensors (alpha/norm folded)
//   cursor   [128 .. +N)         hist -> prefix -> cursor -> row ends
//   zrec     [.. +12E)           per-edge Z records, EDGE order, 48 B each:
//                                q0={src, P(z0,y0), P(z10,z11), P(z12,z30)}
//                                q1={P(z31,z32), P(z40,z41), P(z42,z43), P(z44,z45)}
//                                q2={P(z46,z47), P(z48,0), 0, 0}
//   eorder   [.. +E)             edge ids sorted by dst
//   Tb       [.. +192N)          node table bf16 [N][32][6] words:
//                                u0={a0,a1} u1={b2p0,b2p1} u2={b2p2,b3x}
//                                u3={b3y,b3z} u4={b4x,b4y} u5={b4z,0}
//   tilesums [.. +256)           per-tile sums for hierarchical scan
// ---------------------------------------------------------------------------

__device__ inline float blo(unsigned u) { return __uint_as_float(u << 16); }
__device__ inline float bhi(unsigned u) { return __uint_as_float(u & 0xffff0000u); }
__device__ inline unsigned bpack(float a, float b) {
    unsigned ua = __float_as_uint(a);
    ua = (ua + 0x7fffu + ((ua >> 16) & 1u)) >> 16;
    unsigned ub = __float_as_uint(b);
    ub = (ub + 0x7fffu + ((ub >> 16) & 1u)) & 0xffff0000u;
    return ua | ub;
}

__device__ inline double dfact(int n) {
    double r = 1.0;
    for (int i = 2; i <= n; ++i) r *= (double)i;
    return r;
}

// real->complex spherical harmonic change of basis (e3nn convention)
__device__ void qmat(int l, double qr[5][5], double qi[5][5]) {
    for (int a = 0; a < 5; a++)
        for (int b = 0; b < 5; b++) { qr[a][b] = 0.0; qi[a][b] = 0.0; }
    const double inv = 0.70710678118654752440;
    for (int m = -l; m < 0; ++m) {
        qr[l + m][l - m] = inv;
        qi[l + m][l + m] = -inv;
    }
    qr[l][l] = 1.0;
    for (int m = 1; m <= l; ++m) {
        double sgn = (m & 1) ? -1.0 : 1.0;
        qr[l + m][l + m] = sgn * inv;
        qi[l + m][l - m] = sgn * inv;
    }
    if (l == 1) {          // * (-i)
        for (int a = 0; a < 5; a++)
            for (int b = 0; b < 5; b++) {
                double r = qr[a][b], im = qi[a][b];
                qr[a][b] = im; qi[a][b] = -r;
            }
    } else if (l == 2) {   // * (-1)
        for (int a = 0; a < 5; a++)
            for (int b = 0; b < 5; b++) { qr[a][b] = -qr[a][b]; qi[a][b] = -qi[a][b]; }
    }
}

// SU(2) "CG" element via the reference's exact Racah-form (all six m-dependent
// factorials in the NUMERATOR — non-standard but matches the reference).
__device__ double su2_cg_elem(int l1, int l2, int l3, int i, int k, int n) {
    int m1 = i - l1, m2 = k - l2, m3 = n - l3;
    if (m1 + m2 != m3) return 0.0;
    int vmin = -l1 + l2 + m3;
    if (-l1 + m1 > vmin) vmin = -l1 + m1;
    if (0 > vmin) vmin = 0;
    int vmax = l2 + l3 + m1;
    if (l3 - l1 + l2 < vmax) vmax = l3 - l1 + l2;
    if (l3 + m3 < vmax) vmax = l3 + m3;
    if (vmax < vmin) return 0.0;
    double c = sqrt((double)(2 * l3 + 1) * dfact(l3 + l1 - l2) *
                    dfact(l3 - l1 + l2) * dfact(l1 + l2 - l3) /
                    dfact(l1 + l2 + l3 + 1));
    c *= sqrt(dfact(l3 + m3) * dfact(l3 - m3) * dfact(l1 - m1) *
              dfact(l1 + m1) * dfact(l2 - m2) * dfact(l2 + m2));
    double s = 0.0;
    for (int v = vmin; v <= vmax; ++v) {
        double term = dfact(l2 + l3 + m1 - v) * dfact(l1 - m1 + v) /
                      (dfact(v) * dfact(l3 - l1 + l2 - v) *
                       dfact(l3 + m3 - v) * dfact(v + l1 - l2 - m3));
        if ((v + l2 + m2) & 1) term = -term;
        s += term;
    }
    return c * s;
}

// Parallel CG init: thread t -> (path p = t/45, element idx = t%45).
__global__ void cg_init_kernel(float* __restrict__ cg_out) {
    const int l1s[5] = {0, 0, 1, 1, 1};
    const int l2s[5] = {0, 1, 0, 1, 2};
    const int l3s[5] = {0, 1, 1, 0, 1};
    const int offs[5] = {0, 1, 10, 19, 28};
    const double alphas[5] = {0.125, 0.10206207261596575, 0.10206207261596575,
                              0.125, 0.10206207261596575};
    __shared__ double vals[5][45];
    int t = threadIdx.x;
    int p = t / 45, idx = t % 45;
    bool active = (t < 225);
    double acc = 0.0;
    int d1 = 0, d2 = 0, d3 = 0;
    if (active) {
        int l1 = l1s[p], l2 = l2s[p], l3 = l3s[p];
        d1 = 2 * l1 + 1; d2 = 2 * l2 + 1; d3 = 2 * l3 + 1;
        if (idx < d1 * d2 * d3) {
            int j = idx / (d2 * d3);
            int rem = idx % (d2 * d3);
            int l_ = rem / d3, m = rem % d3;
            double q1r[5][5], q1i[5][5], q2r[5][5], q2i[5][5], q3r[5][5], q3i[5][5];
            qmat(l1, q1r, q1i);
            qmat(l2, q2r, q2i);
            qmat(l3, q3r, q3i);
            for (int i = 0; i < d1; ++i)
                for (int k = 0; k < d2; ++k)
                    for (int n = 0; n < d3; ++n) {
                        double C = su2_cg_elem(l1, l2, l3, i, k, n);
                        if (C == 0.0) continue;
                        double ar = q1r[i][j], ai = q1i[i][j];
                        double br = q2r[k][l_], bi = q2i[k][l_];
                        double cr = q3r[n][m], ci = q3i[n][m];
                        double abr = ar * br - ai * bi;
                        double abi = ar * bi + ai * br;
                        acc += (abr * cr + abi * ci) * C;  // Re(a*b*conj(c))
                    }
        }
        vals[p][idx] = acc;
    }
    __syncthreads();
    if (active && idx < d1 * d2 * d3) {
        double n2 = 0.0;
        for (int q = 0; q < 45; ++q) n2 += vals[p][q] * vals[p][q];
        cg_out[offs[p] + idx] = (float)(acc * alphas[p] / sqrt(n2));
    }
}

// ---------------------------------------------------------------------------
// Node precompute -> bf16 table. c2 (P2's CG) is edge-independent, so fold it
// here: b2p[m] = sum_i b2[i] * c2[i][m].
// ---------------------------------------------------------------------------
__global__ __launch_bounds__(256) void node_precompute(
    const float* __restrict__ feat, const float* __restrict__ W,
    const float* __restrict__ cg, unsigned* __restrict__ Tb, int N) {
    int t = blockIdx.x * 256 + threadIdx.x;
    int n = t >> 5, w = t & 31;
    if (n >= N) return;
    const float* f = feat + (size_t)n * 128;
    float a0 = 0.f, a1 = 0.f;
    float b2x = 0.f, b2y = 0.f, b2z = 0.f;
    float b3x = 0.f, b3y = 0.f, b3z = 0.f;
    float b4x = 0.f, b4y = 0.f, b4z = 0.f;
#pragma unroll 8
    for (int u = 0; u < 32; ++u) {
        float s = f[u];
        float v0 = f[32 + 3 * u], v1 = f[33 + 3 * u], v2 = f[34 + 3 * u];
        float w0 = W[u * 32 + w];
        float w1 = W[1024 + u * 32 + w];
        float w2 = W[2048 + u * 32 + w];
        float w3 = W[3072 + u * 32 + w];
        float w4 = W[4096 + u * 32 + w];
        a0 = fmaf(s, w0, a0);
        a1 = fmaf(s, w1, a1);
        b2x = fmaf(v0, w2, b2x); b2y = fmaf(v1, w2, b2y); b2z = fmaf(v2, w2, b2z);
        b3x = fmaf(v0, w3, b3x); b3y = fmaf(v1, w3, b3y); b3z = fmaf(v2, w3, b3z);
        b4x = fmaf(v0, w4, b4x); b4y = fmaf(v1, w4, b4y); b4z = fmaf(v2, w4, b4z);
    }
    float b2p0 = fmaf(b2x, cg[10], fmaf(b2y, cg[13], b2z * cg[16]));
    float b2p1 = fmaf(b2x, cg[11], fmaf(b2y, cg[14], b2z * cg[17]));
    float b2p2 = fmaf(b2x, cg[12], fmaf(b2y, cg[15], b2z * cg[18]));
    unsigned* Tp = Tb + (size_t)(n * 32 + w) * 6;
    Tp[0] = bpack(a0, a1);
    Tp[1] = bpack(b2p0, b2p1);
    Tp[2] = bpack(b2p2, b3x);
    Tp[3] = bpack(b3y, b3z);
    Tp[4] = bpack(b4x, b4y);
    Tp[5] = bpack(b4z, 0.f);
}

// ---------------------------------------------------------------------------
// zprep: fused histogram + Z-record build. Records written in EDGE order
// (coalesced 48B, 3x dwordx4). No scattered fat writes anywhere.
// ---------------------------------------------------------------------------
__global__ __launch_bounds__(256) void zprep_kernel(
    const int* __restrict__ eidx, const float* __restrict__ sh,
    const float* __restrict__ cg, int* __restrict__ counts,
    unsigned* __restrict__ zrec, int E) {
    int t = blockIdx.x * 256 + threadIdx.x;
    if (t >= E) return;
    atomicAdd(&counts[eidx[E + t]], 1);
    int src = eidx[t];
    const float* Ye = sh + (size_t)t * 9;
    float Y0 = Ye[0];
    float Y1v[3] = {Ye[1], Ye[2], Ye[3]};
    float Y2v[5] = {Ye[4], Ye[5], Ye[6], Ye[7], Ye[8]};
    float Z0 = cg[0] * Y0;
    float Z1[3], Z3[3], Z4[9];
#pragma unroll
    for (int m = 0; m < 3; ++m)
        Z1[m] = fmaf(Y1v[0], cg[1 + m],
                fmaf(Y1v[1], cg[4 + m], Y1v[2] * cg[7 + m]));
#pragma unroll
    for (int i = 0; i < 3; ++i)
        Z3[i] = fmaf(Y1v[0], cg[19 + i * 3],
                fmaf(Y1v[1], cg[19 + i * 3 + 1], Y1v[2] * cg[19 + i * 3 + 2]));
#pragma unroll
    for (int i = 0; i < 3; ++i)
#pragma unroll
        for (int m = 0; m < 3; ++m) {
            float acc = 0.f;
#pragma unroll
            for (int j = 0; j < 5; ++j)
                acc = fmaf(Y2v[j], cg[28 + (i * 5 + j) * 3 + m], acc);
            Z4[i * 3 + m] = acc;
        }
    unsigned* rec = zrec + (size_t)t * 12;
    uint4 q0 = make_uint4((unsigned)src, bpack(Z0, Y0),
                          bpack(Z1[0], Z1[1]), bpack(Z1[2], Z3[0]));
    uint4 q1 = make_uint4(bpack(Z3[1], Z3[2]), bpack(Z4[0], Z4[1]),
                          bpack(Z4[2], Z4[3]), bpack(Z4[4], Z4[5]));
    uint4 q2 = make_uint4(bpack(Z4[6], Z4[7]), bpack(Z4[8], 0.f), 0u, 0u);
    *(uint4*)rec = q0;
    *(uint4*)(rec + 4) = q1;
    *(uint4*)(rec + 8) = q2;
}

// ---------------------------------------------------------------------------
// 3-pass coalesced scan + id-only scatter (4B scattered writes)
// ---------------------------------------------------------------------------
__global__ __launch_bounds__(256) void scanA_kernel(
    const int* __restrict__ counts, int* __restrict__ tilesums, int N) {
    __shared__ int lds[4];
    int i = blockIdx.x * 256 + threadIdx.x;
    int v = (i < N) ? counts[i] : 0;
#pragma unroll
    for (int d = 1; d < 64; d <<= 1) v += __shfl_xor(v, d);
    int wid = threadIdx.x >> 6;
    if ((threadIdx.x & 63) == 0) lds[wid] = v;
    __syncthreads();
    if (threadIdx.x == 0)
        tilesums[blockIdx.x] = lds[0] + lds[1] + lds[2] + lds[3];
}

__global__ __launch_bounds__(256) void scanB_kernel(
    int* __restrict__ tilesums, int tiles) {
    __shared__ int lds[4];
    int tid = threadIdx.x;
    int v = (tid < tiles) ? tilesums[tid] : 0;
    int orig = v;
#pragma unroll
    for (int d = 1; d < 64; d <<= 1) {
        int t = __shfl_up(v, d);
        if ((tid & 63) >= d) v += t;
    }
    int wid = tid >> 6;
    if ((tid & 63) == 63) lds[wid] = v;
    __syncthreads();
    int base = 0;
    for (int q = 0; q < wid; ++q) base += lds[q];
    if (tid < tiles) tilesums[tid] = base + v - orig;  // exclusive
}

__global__ __launch_bounds__(256) void scanC_kernel(
    int* __restrict__ counts, const int* __restrict__ tilesums, int N) {
    __shared__ int lds[4];
    int i = blockIdx.x * 256 + threadIdx.x;
    int tid = threadIdx.x;
    int v = (i < N) ? counts[i] : 0;
    int orig = v;
#pragma unroll
    for (int d = 1; d < 64; d <<= 1) {
        int t = __shfl_up(v, d);
        if ((tid & 63) >= d) v += t;
    }
    int wid = tid >> 6;
    if ((tid & 63) == 63) lds[wid] = v;
    __syncthreads();
    int base = tilesums[blockIdx.x];
    for (int q = 0; q < wid; ++q) base += lds[q];
    if (i < N) counts[i] = base + v - orig;  // exclusive prefix
}

__global__ __launch_bounds__(256) void scatter_ids_kernel(
    const int* __restrict__ eidx, int* __restrict__ cursor,
    int* __restrict__ eorder, int E) {
    int t = blockIdx.x * 256 + threadIdx.x;
    if (t >= E) return;
    int pos = atomicAdd(&cursor[eidx[E + t]], 1);
    eorder[pos] = t;
}
// After scatter: cursor[d] == end of d's range; start(d) = d ? cursor[d-1] : 0.

// ---------------------------------------------------------------------------
// Gather: one 64-lane wave per dst; half-waves take alternate edges; lane
// owns channel w = lane&31. 2-edge unroll per iteration for MLP. 19 FMA/edge.
// ---------------------------------------------------------------------------
__device__ inline void edge_accum(uint4 q0, uint4 q1, uint2 q2,
                                  uint2 T0, uint2 T1, uint2 T2,
                                  float& acc0, float& accx, float& accy,
                                  float& accz) {
    float z0 = blo(q0.y), y0 = bhi(q0.y);
    float z10 = blo(q0.z), z11 = bhi(q0.z), z12 = blo(q0.w), z30 = bhi(q0.w);
    float z31 = blo(q1.x), z32 = bhi(q1.x);
    float z40 = blo(q1.y), z41 = bhi(q1.y), z42 = blo(q1.z), z43 = bhi(q1.z);
    float z44 = blo(q1.w), z45 = bhi(q1.w);
    float z46 = blo(q2.x), z47 = bhi(q2.x), z48 = blo(q2.y);
    float a0 = blo(T0.x), a1 = bhi(T0.x);
    float b2p0 = blo(T0.y), b2p1 = bhi(T0.y), b2p2 = blo(T1.x);
    float b3x = bhi(T1.x), b3y = blo(T1.y), b3z = bhi(T1.y);
    float b4x = blo(T2.x), b4y = bhi(T2.x), b4z = blo(T2.y);
    acc0 = fmaf(z0, a0, acc0);
    acc0 = fmaf(b3x, z30, acc0);
    acc0 = fmaf(b3y, z31, acc0);
    acc0 = fmaf(b3z, z32, acc0);
    accx = fmaf(a1, z10, fmaf(y0, b2p0,
           fmaf(b4x, z40, fmaf(b4y, z43, fmaf(b4z, z46, accx)))));
    accy = fmaf(a1, z11, fmaf(y0, b2p1,
           fmaf(b4x, z41, fmaf(b4y, z44, fmaf(b4z, z47, accy)))));
    accz = fmaf(a1, z12, fmaf(y0, b2p2,
           fmaf(b4x, z42, fmaf(b4y, z45, fmaf(b4z, z48, accz)))));
}

__global__ __launch_bounds__(256) void gather_kernel(
    const unsigned* __restrict__ Tb, const unsigned* __restrict__ zrec,
    const int* __restrict__ eorder, const int* __restrict__ cursor,
    float* __restrict__ out, int N) {
    int wave = (blockIdx.x * 256 + threadIdx.x) >> 6;
    int lane = threadIdx.x & 63;
    if (wave >= N) return;
    int start = wave ? cursor[wave - 1] : 0;
    int end = cursor[wave];
    int half = lane >> 5, w = lane & 31;

    float acc0 = 0.f, accx = 0.f, accy = 0.f, accz = 0.f;
    int idx = start + half;
    while (idx + 2 < end) {  // 2-edge unrolled: idx and idx+2
        int eA = eorder[idx];
        int eB = eorder[idx + 2];
        const unsigned* rA = zrec + (size_t)eA * 12;
        const unsigned* rB = zrec + (size_t)eB * 12;
        uint4 qA0 = *(const uint4*)rA;
        uint4 qA1 = *(const uint4*)(rA + 4);
        uint2 qA2 = *(const uint2*)(rA + 8);
        uint4 qB0 = *(const uint4*)rB;
        uint4 qB1 = *(const uint4*)(rB + 4);
        uint2 qB2 = *(const uint2*)(rB + 8);
        const unsigned* tA = Tb + ((size_t)(int)qA0.x * 32 + w) * 6;
        const unsigned* tB = Tb + ((size_t)(int)qB0.x * 32 + w) * 6;
        uint2 TA0 = *(const uint2*)tA;
        uint2 TA1 = *(const uint2*)(tA + 2);
        uint2 TA2 = *(const uint2*)(tA + 4);
        uint2 TB0 = *(const uint2*)tB;
        uint2 TB1 = *(const uint2*)(tB + 2);
        uint2 TB2 = *(const uint2*)(tB + 4);
        edge_accum(qA0, qA1, qA2, TA0, TA1, TA2, acc0, accx, accy, accz);
        edge_accum(qB0, qB1, qB2, TB0, TB1, TB2, acc0, accx, accy, accz);
        idx += 4;
    }
    if (idx < end) {
        int e = eorder[idx];
        const unsigned* r = zrec + (size_t)e * 12;
        uint4 q0 = *(const uint4*)r;
        uint4 q1 = *(const uint4*)(r + 4);
        uint2 q2 = *(const uint2*)(r + 8);
        const unsigned* tp = Tb + ((size_t)(int)q0.x * 32 + w) * 6;
        uint2 T0 = *(const uint2*)tp;
        uint2 T1 = *(const uint2*)(tp + 2);
        uint2 T2 = *(const uint2*)(tp + 4);
        edge_accum(q0, q1, q2, T0, T1, T2, acc0, accx, accy, accz);
    }
    acc0 += __shfl_xor(acc0, 32);
    accx += __shfl_xor(accx, 32);
    accy += __shfl_xor(accy, 32);
    accz += __shfl_xor(accz, 32);
    if (half == 0) {
        float* ob = out + (size_t)wave * 128;
        ob[w] = acc0;
        float* o1p = ob + 32 + w * 3;
        o1p[0] = accx;
        o1p[1] = accy;
        o1p[2] = accz;
    }
}

extern "C" void kernel_launch(void* const* d_in, const int* in_sizes, int n_in,
                              void* d_out, int out_size, void* d_ws, size_t ws_size,
                              hipStream_t stream) {
    const float* feat = (const float*)d_in[0];
    const float* sh = (const float*)d_in[1];
    const int* eidx = (const int*)d_in[2];
    const float* W = (const float*)d_in[3];
    float* out = (float*)d_out;
    int N = in_sizes[0] / 128;
    int E = in_sizes[1] / 9;

    float* wsf = (float*)d_ws;
    float* cg = wsf;                                   // 128 words
    int* cursor = (int*)(wsf + 128);                   // N
    unsigned* zrec = (unsigned*)(cursor + N);          // 12E
    int* eorder = (int*)(zrec + (size_t)12 * E);       // E
    unsigned* Tb = (unsigned*)(eorder + E);            // 192N
    int* tilesums = (int*)(Tb + (size_t)192 * N);      // 256

    int tiles = (N + 255) / 256;

    cg_init_kernel<<<1, 256, 0, stream>>>(cg);
    node_precompute<<<(N * 32 + 255) / 256, 256, 0, stream>>>(feat, W, cg, Tb, N);
    hipMemsetAsync(cursor, 0, (size_t)N * sizeof(int), stream);
    zprep_kernel<<<(E + 255) / 256, 256, 0, stream>>>(eidx, sh, cg, cursor, zrec, E);
    scanA_kernel<<<tiles, 256, 0, stream>>>(cursor, tilesums, N);
    scanB_kernel<<<1, 256, 0, stream>>>(tilesums, tiles);
    scanC_kernel<<<tiles, 256, 0, stream>>>(cursor, tilesums, N);
    scatter_ids_kernel<<<(E + 255) / 256, 256, 0, stream>>>(eidx, cursor, eorder, E);
    gather_kernel<<<(N * 64 + 255) / 256, 256, 0, stream>>>(Tb, zrec, eorder, cursor, out, N);
}